// Round 3
// baseline (588.202 us; speedup 1.0000x reference)
//
#include <hip/hip_runtime.h>
#include <stdint.h>

#define N_NODES 8192
#define CH 256
#define BM 128
#define BK 64
#define KSPLIT 4
#define KLEN (N_NODES / KSPLIT)  // 2048
#define TILES (KLEN / BK)        // 32
#define NSTAGE 3
#define ZROWS 16
#define ZBLOCKS (N_NODES / ZROWS)  // 512
#define DEGBLOCKS (N_NODES / 4)    // 2048

typedef __bf16 bf16x8 __attribute__((ext_vector_type(8)));
typedef float f32x4 __attribute__((ext_vector_type(4)));
typedef unsigned short u16x4 __attribute__((ext_vector_type(4)));

// ---- async global->LDS, 16B per lane. LDS dest is the WAVE-UNIFORM base;
// HW scatters lane l to base + 16*l.
__device__ __forceinline__ void async_copy16(const void* g, void* l) {
  __builtin_amdgcn_global_load_lds(
      (const __attribute__((address_space(1))) void*)(uintptr_t)g,
      (__attribute__((address_space(3))) void*)(uint32_t)(uintptr_t)l,
      16, 0, 0);
}

__device__ __forceinline__ unsigned short f32_to_bf16_rne(float f) {
  unsigned u = __float_as_uint(f);
  u += 0x7FFFu + ((u >> 16) & 1u);
  return (unsigned short)(u >> 16);
}

__device__ __forceinline__ u16x4 f32x4_to_bf16_rne(f32x4 v) {
  u16x4 r;
  r.x = f32_to_bf16_rne(v.x);
  r.y = f32_to_bf16_rne(v.y);
  r.z = f32_to_bf16_rne(v.z);
  r.w = f32_to_bf16_rne(v.w);
  return r;
}

// ---- Pass 1 (heterogeneous blocks):
//   blocks [0, ZBLOCKS):           z = x @ w  (fp32, 16 rows/block)
//   blocks [ZBLOCKS, ZBLOCKS+2048): deg rowsums (4 rows/block, wave-per-row)
//                                   + write adj as bf16 (RNE) to adjb
// Block 0 additionally zeroes the 64 split-K completion counters (stream-
// ordered before k_gemm1's atomics).
__global__ void __launch_bounds__(256) k_pass1(const float* __restrict__ x,
                                               const float* __restrict__ w,
                                               const float* __restrict__ adj,
                                               float* __restrict__ z,
                                               float* __restrict__ dsq,
                                               unsigned short* __restrict__ adjb,
                                               unsigned int* __restrict__ cnt) {
  __shared__ float xs[ZROWS][CH];
  if (blockIdx.x < ZBLOCKS) {
    if (blockIdx.x == 0 && threadIdx.x < 64) cnt[threadIdx.x] = 0u;
    const int r0 = blockIdx.x * ZROWS;
    const int t = threadIdx.x;
#pragma unroll
    for (int r = 0; r < ZROWS; ++r) xs[r][t] = x[(size_t)(r0 + r) * CH + t];
    __syncthreads();
    float acc[ZROWS];
#pragma unroll
    for (int r = 0; r < ZROWS; ++r) acc[r] = 0.f;
    for (int k = 0; k < CH; k += 8) {
      float wv[8];
#pragma unroll
      for (int u = 0; u < 8; ++u) wv[u] = w[(size_t)(k + u) * CH + t];
#pragma unroll
      for (int r = 0; r < ZROWS; ++r) {
#pragma unroll
        for (int u = 0; u < 8; ++u) acc[r] += xs[r][k + u] * wv[u];
      }
    }
#pragma unroll
    for (int r = 0; r < ZROWS; ++r) z[(size_t)(r0 + r) * CH + t] = acc[r];
  } else {
    const int wave = threadIdx.x >> 6, lane = threadIdx.x & 63;
    const int row = (blockIdx.x - ZBLOCKS) * 4 + wave;
    const f32x4* ar = (const f32x4*)(adj + (size_t)row * N_NODES);
    u16x4* br = (u16x4*)(adjb + (size_t)row * N_NODES);
    float s0 = 0.f, s1 = 0.f, s2 = 0.f, s3 = 0.f;
#pragma unroll
    for (int i = 0; i < 8; ++i) {
      f32x4 a = ar[lane + 64 * (4 * i + 0)];
      f32x4 b = ar[lane + 64 * (4 * i + 1)];
      f32x4 c = ar[lane + 64 * (4 * i + 2)];
      f32x4 d = ar[lane + 64 * (4 * i + 3)];
      br[lane + 64 * (4 * i + 0)] = f32x4_to_bf16_rne(a);
      br[lane + 64 * (4 * i + 1)] = f32x4_to_bf16_rne(b);
      br[lane + 64 * (4 * i + 2)] = f32x4_to_bf16_rne(c);
      br[lane + 64 * (4 * i + 3)] = f32x4_to_bf16_rne(d);
      s0 += (a.x + a.y) + (a.z + a.w);
      s1 += (b.x + b.y) + (b.z + b.w);
      s2 += (c.x + c.y) + (c.z + c.w);
      s3 += (d.x + d.y) + (d.z + d.w);
    }
    float s = (s0 + s1) + (s2 + s3);
#pragma unroll
    for (int off = 32; off > 0; off >>= 1) s += __shfl_down(s, off, 64);
    if (lane == 0) dsq[row] = rsqrtf(s + 1.0f);
  }
}

// ---- Pass 2: yt[c][j] = bf16(dsq[j] * z[j][c])  (transposed, k-contiguous)
__global__ void __launch_bounds__(256) k_y(const float* __restrict__ z,
                                           const float* __restrict__ dsq,
                                           unsigned short* __restrict__ yt) {
  const int r0 = blockIdx.x * 16;
  const int t = threadIdx.x;
  unsigned short vals[16];
#pragma unroll
  for (int r = 0; r < 16; ++r)
    vals[r] = f32_to_bf16_rne(dsq[r0 + r] * z[(size_t)(r0 + r) * CH + t]);
  *(u16x4*)&yt[(size_t)t * N_NODES + r0 + 0] = *(u16x4*)&vals[0];
  *(u16x4*)&yt[(size_t)t * N_NODES + r0 + 4] = *(u16x4*)&vals[4];
  *(u16x4*)&yt[(size_t)t * N_NODES + r0 + 8] = *(u16x4*)&vals[8];
  *(u16x4*)&yt[(size_t)t * N_NODES + r0 + 12] = *(u16x4*)&vals[12];
}

// ---- Pass 3: partial[s] = adjb[:, sK:(s+1)K] @ y[sK:(s+1)K, :]
// BM=128 x 256 output per block, K-split 4 ways -> grid 256 = 1 block/CU.
// s = blockIdx.x & 3: all 32 blocks on an XCD share ONE phase-locked 1MB yt
// slice -> L2-resident B. 8 waves in 2x4 grid, each owns 64x64 output.
// NSTAGE=3 ring, uniform 6 DMAs/wave/tile, counted vmcnt(6).
// NEW: split-K reduction fused via last-block-finalizes semaphore: each block
// stores its f32 partial, release-fences, bumps cnt[panel]; the 4th block
// acquire-fences, re-reads all 4 partials (own L2-hot, siblings L3-hot),
// applies the dsq/identity/ELU epilogue, writes out. Deterministic sum order.
__global__ void __launch_bounds__(512, 1) k_gemm1(const unsigned short* __restrict__ adjb,
                                                  const unsigned short* __restrict__ yt,
                                                  const float* __restrict__ z,
                                                  const float* __restrict__ dsq,
                                                  float* __restrict__ part,
                                                  float* __restrict__ out,
                                                  unsigned int* __restrict__ cnt) {
  __shared__ __align__(16) unsigned short As[NSTAGE][BM * BK];  // 16 KB each
  __shared__ __align__(16) unsigned short Bs[NSTAGE][CH * BK];  // 32 KB each
  __shared__ int last_flag;

  const int tid = threadIdx.x;
  const int wave = tid >> 6;  // 0..7
  const int lane = tid & 63;
  const int s = blockIdx.x & 3;
  const int mblk = blockIdx.x >> 2;
  const int m0 = mblk * BM;
  const int k_base = s * KLEN;
  const int lr = lane & 15;
  const int lq = lane >> 4;
  const int wr = wave >> 2;  // 0..1 (m-dir)
  const int wc = wave & 3;   // 0..3 (n-dir)

  // A staging: tile = 1024 chunks of 16B = 16 wave-instrs; wave w does 2w,2w+1.
  const unsigned short* ag[2];
  int aoff[2];
#pragma unroll
  for (int q = 0; q < 2; ++q) {
    int i = wave * 2 + q;
    int p = 64 * i + lane;
    int r = p >> 3;
    int c8 = (lane & 7) ^ (r & 7);
    ag[q] = adjb + (size_t)(m0 + r) * N_NODES + k_base + c8 * 8;
    aoff[q] = 1024 * i;
  }
  // B staging: 32 instrs, 4 per wave.
  const unsigned short* bg[4];
  int boff[4];
#pragma unroll
  for (int q = 0; q < 4; ++q) {
    int i = wave * 4 + q;
    int p = 64 * i + lane;
    int n = p >> 3;
    int c8 = (lane & 7) ^ (n & 7);
    bg[q] = yt + (size_t)n * N_NODES + k_base + c8 * 8;
    boff[q] = 1024 * i;
  }

  f32x4 acc[4][4];
#pragma unroll
  for (int i = 0; i < 4; ++i)
#pragma unroll
    for (int j = 0; j < 4; ++j) acc[i][j] = (f32x4){0.f, 0.f, 0.f, 0.f};

  auto issue = [&](int b, int k0) {
    char* aL = (char*)&As[b][0];
    char* bL = (char*)&Bs[b][0];
#pragma unroll
    for (int q = 0; q < 2; ++q) async_copy16(ag[q] + k0, aL + aoff[q]);
#pragma unroll
    for (int q = 0; q < 4; ++q) async_copy16(bg[q] + k0, bL + boff[q]);
  };

  auto compute = [&](int b) {
    const char* aB = (const char*)&As[b][0];
    const char* bB = (const char*)&Bs[b][0];
#pragma unroll
    for (int k32 = 0; k32 < 2; ++k32) {
      const int c8 = k32 * 4 + lq;
      bf16x8 afr[4];
#pragma unroll
      for (int mt = 0; mt < 4; ++mt) {
        int row = wr * 64 + mt * 16 + lr;
        int p = row * 8 + (c8 ^ (row & 7));
        afr[mt] = *(const bf16x8*)(aB + p * 16);
      }
      __builtin_amdgcn_s_setprio(1);
#pragma unroll
      for (int nt = 0; nt < 4; ++nt) {
        int n = wc * 64 + nt * 16 + lr;
        int p = n * 8 + (c8 ^ (n & 7));
        bf16x8 bfr = *(const bf16x8*)(bB + p * 16);
#pragma unroll
        for (int mt = 0; mt < 4; ++mt)
          acc[mt][nt] = __builtin_amdgcn_mfma_f32_16x16x32_bf16(afr[mt], bfr, acc[mt][nt], 0, 0, 0);
      }
      __builtin_amdgcn_s_setprio(0);
    }
  };

  // Prologue: 2 tiles in flight (tile t lives in buffer t % 3).
  issue(0, 0);
  issue(1, BK);

  int bc = 0;  // buffer of tile kb
  for (int kb = 0; kb < TILES - 1; ++kb) {
    asm volatile("s_waitcnt vmcnt(6)" ::: "memory");
    __builtin_amdgcn_s_barrier();
    __builtin_amdgcn_sched_barrier(0);
    if (kb + 2 < TILES) {
      int bi = bc + 2;
      if (bi >= NSTAGE) bi -= NSTAGE;
      issue(bi, (kb + 2) * BK);
    }
    compute(bc);
    __builtin_amdgcn_sched_barrier(0);
    bc = (bc + 1 == NSTAGE) ? 0 : bc + 1;
  }
  asm volatile("s_waitcnt vmcnt(0)" ::: "memory");
  __builtin_amdgcn_s_barrier();
  __builtin_amdgcn_sched_barrier(0);
  compute(bc);

  // store f32 partial (quarter-wave coalesced 64B groups)
  const size_t SP = (size_t)N_NODES * CH;
  float* Ps = part + (size_t)s * SP;
#pragma unroll
  for (int mt = 0; mt < 4; ++mt) {
#pragma unroll
    for (int r = 0; r < 4; ++r) {
      int row = m0 + wr * 64 + mt * 16 + lq * 4 + r;
#pragma unroll
      for (int nt = 0; nt < 4; ++nt) {
        int col = wc * 64 + nt * 16 + lr;
        Ps[(size_t)row * CH + col] = acc[mt][nt][r];
      }
    }
  }

  // ---- last-block-finalizes split-K reduction ----
  __threadfence();   // release: publish this block's partial (all threads)
  __syncthreads();   // all threads' stores+fences done before the atomic
  if (tid == 0) {
    unsigned old = atomicAdd(&cnt[mblk], 1u);  // device scope
    last_flag = (old == 3);
  }
  __syncthreads();
  if (!last_flag) return;
  __threadfence();   // acquire: invalidate stale cached lines before reads

  const size_t base = (size_t)m0 * CH;
  const f32x4* p0 = (const f32x4*)(part + base);
  const f32x4* p1 = (const f32x4*)(part + base + SP);
  const f32x4* p2 = (const f32x4*)(part + base + 2 * SP);
  const f32x4* p3 = (const f32x4*)(part + base + 3 * SP);
  const f32x4* zz = (const f32x4*)(z + base);
  f32x4* oo = (f32x4*)(out + base);
  // panel = 128x256 f32 = 8192 f32x4; 512 threads x 16 vecs
#pragma unroll
  for (int j = 0; j < 16; ++j) {
    int v = tid + 512 * j;
    int row = v >> 6;  // 64 f32x4 per row
    float di = dsq[m0 + row];
    f32x4 sum = (p0[v] + p1[v]) + (p2[v] + p3[v]);
    f32x4 zv = zz[v];
    f32x4 r;
#pragma unroll
    for (int l = 0; l < 4; ++l) {
      float val = di * (sum[l] + di * zv[l]);
      r[l] = val > 0.f ? val : expm1f(val);
    }
    oo[v] = r;
  }
}

extern "C" void kernel_launch(void* const* d_in, const int* in_sizes, int n_in,
                              void* d_out, int out_size, void* d_ws, size_t ws_size,
                              hipStream_t stream) {
  const float* x = (const float*)d_in[0];
  const float* adj = (const float*)d_in[1];
  const float* w = (const float*)d_in[2];
  float* out = (float*)d_out;

  // ws layout: dsq @0 (32KB) ; yt @32768 (4MB) ; z @4227072 (8MB) ;
  //            adjb @12615680 (134MB) ; part @146833408 (32MB) ;
  //            cnt @180387840 (256B)
  float* dsq = (float*)d_ws;
  unsigned short* yt = (unsigned short*)((char*)d_ws + 32768);
  float* z = (float*)((char*)d_ws + 4227072);
  unsigned short* adjb = (unsigned short*)((char*)d_ws + 12615680);
  float* part = (float*)((char*)d_ws + 146833408);
  unsigned int* cnt = (unsigned int*)((char*)d_ws + 180387840);

  k_pass1<<<ZBLOCKS + DEGBLOCKS, 256, 0, stream>>>(x, w, adj, z, dsq, adjb, cnt);
  k_y<<<N_NODES / 16, 256, 0, stream>>>(z, dsq, yt);
  k_gemm1<<<N_NODES / BM * KSPLIT, 512, 0, stream>>>(adjb, yt, z, dsq, part, out, cnt);
}

// Round 4
// 449.276 us; speedup vs baseline: 1.3092x; 1.3092x over previous
//
#include <hip/hip_runtime.h>
#include <stdint.h>

#define N_NODES 8192
#define CH 256
#define BM 128
#define BK 64
#define KSPLIT 4
#define KLEN (N_NODES / KSPLIT)  // 2048
#define TILES (KLEN / BK)        // 32
#define ZROWS 16
#define ZBLOCKS (N_NODES / ZROWS)  // 512
#define DEGBLOCKS (N_NODES / 4)    // 2048

typedef __bf16 bf16x8 __attribute__((ext_vector_type(8)));
typedef float f32x4 __attribute__((ext_vector_type(4)));
typedef unsigned short u16x4 __attribute__((ext_vector_type(4)));

__device__ __forceinline__ unsigned short f32_to_bf16_rne(float f) {
  unsigned u = __float_as_uint(f);
  u += 0x7FFFu + ((u >> 16) & 1u);
  return (unsigned short)(u >> 16);
}

__device__ __forceinline__ u16x4 f32x4_to_bf16_rne(f32x4 v) {
  u16x4 r;
  r.x = f32_to_bf16_rne(v.x);
  r.y = f32_to_bf16_rne(v.y);
  r.z = f32_to_bf16_rne(v.z);
  r.w = f32_to_bf16_rne(v.w);
  return r;
}

// ---- Pass 1 (heterogeneous blocks):
//   blocks [0, ZBLOCKS):           z = x @ w  (fp32, 16 rows/block)
//   blocks [ZBLOCKS, ZBLOCKS+2048): deg rowsums (4 rows/block, wave-per-row)
//                                   + write adj as bf16 (RNE) to adjb
__global__ void __launch_bounds__(256) k_pass1(const float* __restrict__ x,
                                               const float* __restrict__ w,
                                               const float* __restrict__ adj,
                                               float* __restrict__ z,
                                               float* __restrict__ dsq,
                                               unsigned short* __restrict__ adjb) {
  __shared__ float xs[ZROWS][CH];
  if (blockIdx.x < ZBLOCKS) {
    const int r0 = blockIdx.x * ZROWS;
    const int t = threadIdx.x;
#pragma unroll
    for (int r = 0; r < ZROWS; ++r) xs[r][t] = x[(size_t)(r0 + r) * CH + t];
    __syncthreads();
    float acc[ZROWS];
#pragma unroll
    for (int r = 0; r < ZROWS; ++r) acc[r] = 0.f;
    for (int k = 0; k < CH; k += 8) {
      float wv[8];
#pragma unroll
      for (int u = 0; u < 8; ++u) wv[u] = w[(size_t)(k + u) * CH + t];
#pragma unroll
      for (int r = 0; r < ZROWS; ++r) {
#pragma unroll
        for (int u = 0; u < 8; ++u) acc[r] += xs[r][k + u] * wv[u];
      }
    }
#pragma unroll
    for (int r = 0; r < ZROWS; ++r) z[(size_t)(r0 + r) * CH + t] = acc[r];
  } else {
    const int wave = threadIdx.x >> 6, lane = threadIdx.x & 63;
    const int row = (blockIdx.x - ZBLOCKS) * 4 + wave;
    const f32x4* ar = (const f32x4*)(adj + (size_t)row * N_NODES);
    u16x4* br = (u16x4*)(adjb + (size_t)row * N_NODES);
    float s0 = 0.f, s1 = 0.f, s2 = 0.f, s3 = 0.f;
#pragma unroll
    for (int i = 0; i < 8; ++i) {
      f32x4 a = ar[lane + 64 * (4 * i + 0)];
      f32x4 b = ar[lane + 64 * (4 * i + 1)];
      f32x4 c = ar[lane + 64 * (4 * i + 2)];
      f32x4 d = ar[lane + 64 * (4 * i + 3)];
      br[lane + 64 * (4 * i + 0)] = f32x4_to_bf16_rne(a);
      br[lane + 64 * (4 * i + 1)] = f32x4_to_bf16_rne(b);
      br[lane + 64 * (4 * i + 2)] = f32x4_to_bf16_rne(c);
      br[lane + 64 * (4 * i + 3)] = f32x4_to_bf16_rne(d);
      s0 += (a.x + a.y) + (a.z + a.w);
      s1 += (b.x + b.y) + (b.z + b.w);
      s2 += (c.x + c.y) + (c.z + c.w);
      s3 += (d.x + d.y) + (d.z + d.w);
    }
    float s = (s0 + s1) + (s2 + s3);
#pragma unroll
    for (int off = 32; off > 0; off >>= 1) s += __shfl_down(s, off, 64);
    if (lane == 0) dsq[row] = rsqrtf(s + 1.0f);
  }
}

// ---- Pass 2: yt[c][j] = bf16(dsq[j] * z[j][c])  (transposed, k-contiguous)
__global__ void __launch_bounds__(256) k_y(const float* __restrict__ z,
                                           const float* __restrict__ dsq,
                                           unsigned short* __restrict__ yt) {
  const int r0 = blockIdx.x * 16;
  const int t = threadIdx.x;
  unsigned short vals[16];
#pragma unroll
  for (int r = 0; r < 16; ++r)
    vals[r] = f32_to_bf16_rne(dsq[r0 + r] * z[(size_t)(r0 + r) * CH + t]);
  *(u16x4*)&yt[(size_t)t * N_NODES + r0 + 0] = *(u16x4*)&vals[0];
  *(u16x4*)&yt[(size_t)t * N_NODES + r0 + 4] = *(u16x4*)&vals[4];
  *(u16x4*)&yt[(size_t)t * N_NODES + r0 + 8] = *(u16x4*)&vals[8];
  *(u16x4*)&yt[(size_t)t * N_NODES + r0 + 12] = *(u16x4*)&vals[12];
}

// ---- Pass 3: partial[s] = adjb[:, sK:(s+1)K] @ y[sK:(s+1)K, :]
// BM=128 x 256 output per block, K-split 4 ways -> grid 256 = 1 block/CU.
// s = blockIdx.x & 3 is CONSTANT per XCD (blockIdx%8 = XCD) -> each XCD's
// 32 blocks share one 1MB yt slice -> L2-resident B.
// NEW (T14): register-staged global->reg->LDS replaces global_load_lds.
// R3 counters showed the DMA path latency-serializing (225us, 7% HBM,
// MfmaUtil 5.8%); normal vector loads scoreboard deeply per-wave, and the
// compiler's data-dep waitcnts do the counting. 2 LDS buffers, 2 explicit
// register sets (static indexing), 2-tile lookahead covers HBM latency.
// Raw s_barrier + lgkmcnt(0) (NOT __syncthreads) so in-flight global loads
// are never drained at the barrier.
__global__ void __launch_bounds__(512, 1) k_gemm1(const unsigned short* __restrict__ adjb,
                                                  const unsigned short* __restrict__ yt,
                                                  float* __restrict__ part) {
  __shared__ __align__(16) unsigned short As[2][BM * BK];  // 16 KB each
  __shared__ __align__(16) unsigned short Bs[2][CH * BK];  // 32 KB each

  const int tid = threadIdx.x;
  const int wave = tid >> 6;  // 0..7
  const int lane = tid & 63;
  const int s = blockIdx.x & 3;
  const int m0 = (blockIdx.x >> 2) * BM;
  const int k_base = s * KLEN;
  const int lr = lane & 15;
  const int lq = lane >> 4;
  const int wr = wave >> 2;  // 0..1 (m-dir)
  const int wc = wave & 3;   // 0..3 (n-dir)

  // A staging: tile = 1024 chunks of 16B = 16 wave-instrs; wave w does 2w,2w+1.
  // Chunk p = 64i+lane: r = p>>3, source chunk c8 = (lane&7)^(r&7) (XOR swizzle).
  const unsigned short* ag[2];
#pragma unroll
  for (int q = 0; q < 2; ++q) {
    int i = wave * 2 + q;
    int p = 64 * i + lane;
    int r = p >> 3;
    int c8 = (lane & 7) ^ (r & 7);
    ag[q] = adjb + (size_t)(m0 + r) * N_NODES + k_base + c8 * 8;
  }
  // B staging: 32 wave-instrs, 4 per wave.
  const unsigned short* bg[4];
#pragma unroll
  for (int q = 0; q < 4; ++q) {
    int i = wave * 4 + q;
    int p = 64 * i + lane;
    int n = p >> 3;
    int c8 = (lane & 7) ^ (n & 7);
    bg[q] = yt + (size_t)n * N_NODES + k_base + c8 * 8;
  }
  // LDS write bases (linear chunk order; per-buffer offset added per call)
  char* awp = (char*)&As[0][0] + (size_t)(wave * 2 * 64 + lane) * 16;
  char* bwp = (char*)&Bs[0][0] + (size_t)(wave * 4 * 64 + lane) * 16;

  f32x4 acc[4][4];
#pragma unroll
  for (int i = 0; i < 4; ++i)
#pragma unroll
    for (int j = 0; j < 4; ++j) acc[i][j] = (f32x4){0.f, 0.f, 0.f, 0.f};

  auto loadT = [&](int k0, bf16x8 (&ra)[2], bf16x8 (&rb)[4]) {
#pragma unroll
    for (int q = 0; q < 2; ++q) ra[q] = *(const bf16x8*)(ag[q] + k0);
#pragma unroll
    for (int q = 0; q < 4; ++q) rb[q] = *(const bf16x8*)(bg[q] + k0);
  };
  auto writeT = [&](int b, bf16x8 (&ra)[2], bf16x8 (&rb)[4]) {
#pragma unroll
    for (int q = 0; q < 2; ++q) *(bf16x8*)(awp + q * 1024 + b * 16384) = ra[q];
#pragma unroll
    for (int q = 0; q < 4; ++q) *(bf16x8*)(bwp + q * 1024 + b * 32768) = rb[q];
  };
  auto compute = [&](int b) {
    const char* aB = (const char*)&As[0][0] + b * 16384;
    const char* bB = (const char*)&Bs[0][0] + b * 32768;
#pragma unroll
    for (int k32 = 0; k32 < 2; ++k32) {
      const int c8 = k32 * 4 + lq;
      bf16x8 afr[4];
#pragma unroll
      for (int mt = 0; mt < 4; ++mt) {
        int row = wr * 64 + mt * 16 + lr;
        int p = row * 8 + (c8 ^ (row & 7));
        afr[mt] = *(const bf16x8*)(aB + p * 16);
      }
      __builtin_amdgcn_s_setprio(1);
#pragma unroll
      for (int nt = 0; nt < 4; ++nt) {
        int n = wc * 64 + nt * 16 + lr;
        int p = n * 8 + (c8 ^ (n & 7));
        bf16x8 bfr = *(const bf16x8*)(bB + p * 16);
#pragma unroll
        for (int mt = 0; mt < 4; ++mt)
          acc[mt][nt] = __builtin_amdgcn_mfma_f32_16x16x32_bf16(afr[mt], bfr, acc[mt][nt], 0, 0, 0);
      }
      __builtin_amdgcn_s_setprio(0);
    }
  };
  auto syncit = [&]() {
    asm volatile("s_waitcnt lgkmcnt(0)" ::: "memory");
    __builtin_amdgcn_sched_barrier(0);
    __builtin_amdgcn_s_barrier();
    __builtin_amdgcn_sched_barrier(0);
  };

  // Two explicit register sets: tile t lives in set[t&1]. All indexing static.
  bf16x8 ra0[2], rb0[4], ra1[2], rb1[4];

  // Prologue: load tiles 0,1; publish tile 0.
  loadT(0, ra0, rb0);
  loadT(BK, ra1, rb1);
  writeT(0, ra0, rb0);  // compiler inserts exact vmcnt wait for set0 only
  syncit();

  // Main: pairs (kb even, kb+1 odd), kb = 0..TILES-3.
  // body(kb): load tile kb+2 -> set[kb&1]; compute buf[kb&1];
  //           ds_write tile kb+1 from set[(kb+1)&1] -> buf[(kb+1)&1]; sync.
  for (int kb = 0; kb < TILES - 2; kb += 2) {
    loadT((kb + 2) * BK, ra0, rb0);
    compute(0);
    writeT(1, ra1, rb1);
    syncit();
    loadT((kb + 3) * BK, ra1, rb1);
    compute(1);
    writeT(0, ra0, rb0);
    syncit();
  }
  // Tail: tile TILES-2 in buf0; tile TILES-1 still in set1 regs.
  compute(0);
  writeT(1, ra1, rb1);
  syncit();
  compute(1);

  // store f32 partial (quarter-wave coalesced 64B groups)
  const size_t SP = (size_t)N_NODES * CH;
  float* Ps = part + (size_t)s * SP;
#pragma unroll
  for (int mt = 0; mt < 4; ++mt) {
#pragma unroll
    for (int r = 0; r < 4; ++r) {
      int row = m0 + wr * 64 + mt * 16 + lq * 4 + r;
#pragma unroll
      for (int nt = 0; nt < 4; ++nt) {
        int col = wc * 64 + nt * 16 + lr;
        Ps[(size_t)row * CH + col] = acc[mt][nt][r];
      }
    }
  }
}

// ---- Pass 4: out = elu(dsq_i * (sum_s part[s] + dsq_i * z_i))
__global__ void __launch_bounds__(256) k_fin(const float* __restrict__ part,
                                             const float* __restrict__ z,
                                             const float* __restrict__ dsq,
                                             float* __restrict__ out) {
  const int r0 = blockIdx.x * 16;
  const int t = threadIdx.x;
  const size_t SP = (size_t)N_NODES * CH;
#pragma unroll
  for (int r = 0; r < 16; ++r) {
    const int row = r0 + r;
    const size_t idx = (size_t)row * CH + t;
    float sum = (part[idx] + part[idx + SP]) + (part[idx + 2 * SP] + part[idx + 3 * SP]);
    float di = dsq[row];
    float v = di * (sum + di * z[idx]);
    v = v > 0.f ? v : expm1f(v);
    out[idx] = v;
  }
}

extern "C" void kernel_launch(void* const* d_in, const int* in_sizes, int n_in,
                              void* d_out, int out_size, void* d_ws, size_t ws_size,
                              hipStream_t stream) {
  const float* x = (const float*)d_in[0];
  const float* adj = (const float*)d_in[1];
  const float* w = (const float*)d_in[2];
  float* out = (float*)d_out;

  // ws layout: dsq @0 (32KB) ; yt @32768 (4MB) ; z @4227072 (8MB) ;
  //            adjb @12615680 (134MB) ; part @146833408 (32MB)
  float* dsq = (float*)d_ws;
  unsigned short* yt = (unsigned short*)((char*)d_ws + 32768);
  float* z = (float*)((char*)d_ws + 4227072);
  unsigned short* adjb = (unsigned short*)((char*)d_ws + 12615680);
  float* part = (float*)((char*)d_ws + 146833408);

  k_pass1<<<ZBLOCKS + DEGBLOCKS, 256, 0, stream>>>(x, w, adj, z, dsq, adjb);
  k_y<<<N_NODES / 16, 256, 0, stream>>>(z, dsq, yt);
  k_gemm1<<<N_NODES / BM * KSPLIT, 512, 0, stream>>>(adjb, yt, part);
  k_fin<<<N_NODES / 16, 256, 0, stream>>>(part, z, dsq, out);
}